// Round 1
// 259.562 us; speedup vs baseline: 1.0379x; 1.0379x over previous
//
#include <hip/hip_runtime.h>

// ---------------------------------------------------------------------------
// context = softmax((q@Wq+bq)(k@Wk+bk)^T / 32) @ (v@Wv+bv)
// S=4096, H=D=1024. fp32 in/out, bf16 MFMA internally.
//
// GEMM core (gemm256): 256x256 tile, 512 threads (8 waves, 2x4), K processed
// in 32-wide chunks through a 4-unit LDS ring (4 x 32KB = 128KB).
// Per-phase: {12x ds_read_b128 | stage chunk c+3 via global_load_lds x4 |
//             s_barrier | setprio(1) 32x MFMA setprio(0) |
//             counted s_waitcnt vmcnt(8) | s_barrier}.
// vmcnt never drains to 0 in the main loop (T4); [256][32] LDS layout is
// bank-conflict-minimal for the (lr,lq) fragment reads (no swizzle needed,
// so global_load_lds direct staging stays legal).
//
// ws layout (MB):
//   [ 0, 6)  Wt  bf16 [3][1024][1024]      (W^T, per projection)
//   [ 6,30)  xb  bf16 [3][4096][1024]      (q,k,v cast)
//   [30,54)  pr  bf16 [3][4096][1024]      (Q,K,Vn projections; z-contiguous)
//   [54,62)  (Vn tail is pr z=2 @ [46,54)) -- see below
//   [46,78)  S   bf16 [4096][4096]         (overwrites dead Vn after transpose)
//   [78,86)  Vt  bf16 [1024][4096]
//   [ 0,16)  p1, [16,32) p2  fp32 partials (dead Wt/xb region at PV time)
//   [86,102) p3 fp32 partial               (only if ws_size >= 102MB -> SK=4)
// ---------------------------------------------------------------------------

typedef short short4v __attribute__((ext_vector_type(4)));
typedef short short8  __attribute__((ext_vector_type(8)));
typedef float f32x4   __attribute__((ext_vector_type(4)));

#define MFMA16 __builtin_amdgcn_mfma_f32_16x16x32_bf16

__device__ __forceinline__ short f2bf(float f) {
    union { float f; unsigned u; } x; x.f = f;
    unsigned r = (x.u + 0x7FFFu + ((x.u >> 16) & 1u)) >> 16;  // RNE
    return (short)r;
}
__device__ __forceinline__ float bf2f(short s) {
    union { unsigned u; float f; } x;
    x.u = ((unsigned)(unsigned short)s) << 16; return x.f;
}
__device__ __forceinline__ void store_out(short* p, float v) { *p = f2bf(v); }
__device__ __forceinline__ void store_out(float* p, float v) { *p = v; }

// async global->LDS, 16B/lane. LDS dest = wave-uniform base + lane*16.
__device__ __forceinline__ void gl2lds(const short* g, short* l) {
    __builtin_amdgcn_global_load_lds(
        (const __attribute__((address_space(1))) void*)g,
        (__attribute__((address_space(3))) void*)l, 16, 0, 0);
}

// --- W[k][n] fp32 -> Wt[z][n][k] bf16 ------------------------------------
__global__ __launch_bounds__(256) void prep_w(
    const float* __restrict__ W0, const float* __restrict__ W1,
    const float* __restrict__ W2, short* __restrict__ Wt)
{
    __shared__ float tile[64][65];
    const float* W = blockIdx.z == 0 ? W0 : (blockIdx.z == 1 ? W1 : W2);
    short* T = Wt + (size_t)blockIdx.z * 1048576;
    const int c0 = blockIdx.x * 64;
    const int r0 = blockIdx.y * 64;
    const int tx = threadIdx.x & 63;
    const int ty = threadIdx.x >> 6;
    #pragma unroll
    for (int p = 0; p < 16; ++p) {
        int r = ty + p * 4;
        tile[r][tx] = W[(size_t)(r0 + r) * 1024 + c0 + tx];
    }
    __syncthreads();
    #pragma unroll
    for (int p = 0; p < 16; ++p) {
        int r = ty + p * 4;
        T[(size_t)(c0 + r) * 1024 + r0 + tx] = f2bf(tile[tx][r]);
    }
}

// --- q,k,v fp32 -> xb bf16 -----------------------------------------------
__global__ __launch_bounds__(256) void cast_qkv(
    const float* __restrict__ q, const float* __restrict__ k,
    const float* __restrict__ v, short* __restrict__ xb)
{
    const float* src = blockIdx.z == 0 ? q : (blockIdx.z == 1 ? k : v);
    short* dst = xb + (size_t)blockIdx.z * 4194304;
    for (int i = blockIdx.x * 256 + threadIdx.x; i < 1048576; i += 256 * 1024) {
        float4 f = ((const float4*)src)[i];
        short4v o;
        o[0] = f2bf(f.x); o[1] = f2bf(f.y); o[2] = f2bf(f.z); o[3] = f2bf(f.w);
        ((short4v*)dst)[i] = o;
    }
}

// --- Vn bf16 [4096][1024] -> Vt bf16 [1024][4096] -------------------------
__global__ __launch_bounds__(256) void transpose_v(
    const short* __restrict__ src, short* __restrict__ dst)
{
    __shared__ short t[64][65];
    const int c0 = blockIdx.x * 64;   // src col block (dst row block)
    const int r0 = blockIdx.y * 64;   // src row block
    const int tx = threadIdx.x & 63;
    const int ty = threadIdx.x >> 6;
    #pragma unroll
    for (int p = 0; p < 16; ++p) {
        const int r = p * 4 + ty;
        t[r][tx] = src[(size_t)(r0 + r) * 1024 + c0 + tx];
    }
    __syncthreads();
    #pragma unroll
    for (int p = 0; p < 16; ++p) {
        const int r = p * 4 + ty;
        dst[(size_t)(c0 + r) * 4096 + r0 + tx] = t[tx][r];
    }
}

// --- bf16 GEMM core: C = scale*(A @ Bt^T) [+ bias] ------------------------
// 256x256 tile, 8 waves (2Mx4N), 4-unit LDS ring of K=32 chunks.
// MODE 0: plain. MODE 1: z selects {A,Bt,C,bias} (batched projections).
// MODE 2: z is split-K index; C-dst = {C, P1, P2, P3}[z].
template <typename TOut, int MODE>
__global__ __launch_bounds__(512, 2) void gemm256(
    const short* __restrict__ A, const short* __restrict__ Bt,
    const float* __restrict__ b0, const float* __restrict__ b1,
    const float* __restrict__ b2,
    TOut* __restrict__ C, float* __restrict__ P1, float* __restrict__ P2,
    float* __restrict__ P3,
    int M, int N, int lda, int ldb, float scale,
    int nc, int nc_last, int kstep)
{
    // 4 units x { A [256][32] , B [256][32] } bf16 = 4 x 32KB = 128KB
    __shared__ short Lds[65536];

    const int t    = threadIdx.x;
    const int lane = t & 63;
    const int wv   = t >> 6;

    // ---- grid swizzle (XCD L2 locality). HW round-robins bid%8 -> XCD. ---
    int m0, n0;
    {
        const int nb  = gridDim.x;                    // n-tiles
        const int bid = blockIdx.y * nb + blockIdx.x;
        if (nb == 16 && gridDim.y == 16) {
            // 2x4 XCD rectangles: XCD x gets an 8m x 4n block of tiles.
            const int x = bid & 7, i = bid >> 3;
            m0 = ((x & 1) * 8 + (i & 7)) * 256;
            n0 = ((x >> 1) * 4 + (i >> 3)) * 256;
        } else {
            // band swizzle: 8 m-tiles per band, XCD x keeps m == x (mod 8).
            const int band   = bid / (8 * nb);
            const int within = bid - band * 8 * nb;
            m0 = (band * 8 + (within & 7)) * 256;
            n0 = (within >> 3) * 256;
        }
    }

    const float* bias = nullptr;
    int kbeg = 0;
    TOut* Cw = C;
    if constexpr (MODE == 1) {
        const int z = blockIdx.z;
        A  += (size_t)z * M * lda;
        Bt += (size_t)z * N * ldb;
        Cw  = C + (size_t)z * M * N;
        bias = z == 0 ? b0 : (z == 1 ? b1 : b2);
    }
    if constexpr (MODE == 2) {
        const int z = blockIdx.z;
        kbeg = z * kstep;
        if (z == (int)gridDim.z - 1) nc = nc_last;
        Cw = (TOut*)(z == 0 ? (float*)C : (z == 1 ? P1 : (z == 2 ? P2 : P3)));
    }
    (void)b0; (void)b1; (void)b2; (void)P1; (void)P2; (void)P3;
    (void)nc_last; (void)kstep;

    // ---- staging map: per chunk, each wave issues 4 gl2lds (1KB each). ---
    // A rows: block wv -> rows [wv*16,wv*16+16) and +128; B same on n0.
    // lane l covers row += l>>2, k-off (l&3)*8 -> matches LDS base + l*16.
    const int srow = lane >> 2;
    const int skof = (lane & 3) * 8;
    const short* pA0 = A  + (size_t)(m0 + wv * 16 + srow) * lda + kbeg + skof;
    const short* pA1 = pA0 + (size_t)128 * lda;
    const short* pB0 = Bt + (size_t)(n0 + wv * 16 + srow) * ldb + kbeg + skof;
    const short* pB1 = pB0 + (size_t)128 * ldb;
    short* sA0 = Lds + wv * 512;            // wave-uniform LDS bases (shorts)
    short* sA1 = Lds + 4096  + wv * 512;
    short* sB0 = Lds + 8192  + wv * 512;
    short* sB1 = Lds + 12288 + wv * 512;

    // ---- fragment read map (16x16x32: lane = lr + 16*lq) -----------------
    const int wm = wv >> 2, wn = wv & 3;
    const int lr = lane & 15, lq = lane >> 4;
    const short* rdA = Lds + (wm * 128 + lr) * 32 + lq * 8;
    const short* rdB = Lds + 8192 + (wn * 64 + lr) * 32 + lq * 8;

    f32x4 acc[8][4];
    #pragma unroll
    for (int i = 0; i < 8; ++i)
        #pragma unroll
        for (int j = 0; j < 4; ++j) { f32x4 z4 = {0.f,0.f,0.f,0.f}; acc[i][j] = z4; }

#define STAGE(c) {                                                        \
    const int su_ = (c) & 3;                                              \
    const size_t ko_ = (size_t)(c) * 32;                                  \
    gl2lds(pA0 + ko_, sA0 + su_ * 16384);                                 \
    gl2lds(pA1 + ko_, sA1 + su_ * 16384);                                 \
    gl2lds(pB0 + ko_, sB0 + su_ * 16384);                                 \
    gl2lds(pB1 + ko_, sB1 + su_ * 16384); }

    // prologue: chunks 0,1,2 in flight; wait chunk 0 (8 = 2 chunks x 4).
    STAGE(0); STAGE(1); STAGE(2);
    asm volatile("s_waitcnt vmcnt(8)" ::: "memory");
    __builtin_amdgcn_s_barrier();

    // Phase c: reads chunk c (safe: prev phase ended vmcnt+barrier),
    // stages chunk c+3 into the slot chunk c-1 vacated (prev-phase barrier
    // guarantees all waves' reads of c-1 completed before this issue).
#define PHASE(c, DOSTAGE, VMN) {                                          \
    const int u_ = (c) & 3;                                               \
    const short* rA_ = rdA + u_ * 16384;                                  \
    const short* rB_ = rdB + u_ * 16384;                                  \
    short8 af[8], bfr[4];                                                 \
    _Pragma("unroll") for (int i = 0; i < 8; ++i)                         \
        af[i] = *(const short8*)(rA_ + i * 512);                          \
    _Pragma("unroll") for (int j = 0; j < 4; ++j)                         \
        bfr[j] = *(const short8*)(rB_ + j * 512);                         \
    if (DOSTAGE) STAGE((c) + 3);                                          \
    __builtin_amdgcn_s_barrier();                                         \
    __builtin_amdgcn_s_setprio(1);                                        \
    _Pragma("unroll") for (int i = 0; i < 8; ++i)                         \
        _Pragma("unroll") for (int j = 0; j < 4; ++j)                     \
            acc[i][j] = MFMA16(af[i], bfr[j], acc[i][j], 0, 0, 0);        \
    __builtin_amdgcn_s_setprio(0);                                        \
    if ((VMN) == 8)      asm volatile("s_waitcnt vmcnt(8)" ::: "memory"); \
    else if ((VMN) == 4) asm volatile("s_waitcnt vmcnt(4)" ::: "memory"); \
    else if ((VMN) == 0) asm volatile("s_waitcnt vmcnt(0)" ::: "memory"); \
    if ((VMN) >= 0) __builtin_amdgcn_s_barrier(); }

    #pragma unroll 4
    for (int c = 0; c < nc - 3; ++c) PHASE(c, 1, 8);
    PHASE(nc - 3, 0, 4);
    PHASE(nc - 2, 0, 0);
    PHASE(nc - 1, 0, -1);
#undef PHASE
#undef STAGE

    // ---- epilogue: C/D layout col=lane&15, row=(lane>>4)*4+reg -----------
    #pragma unroll
    for (int i = 0; i < 8; ++i) {
        const int crow = m0 + wm * 128 + i * 16 + lq * 4;
        #pragma unroll
        for (int j = 0; j < 4; ++j) {
            const int ccol = n0 + wn * 64 + j * 16 + lr;
            float bb = 0.f;
            if constexpr (MODE == 1) bb = bias[ccol];
            #pragma unroll
            for (int r = 0; r < 4; ++r) {
                float val = acc[i][j][r] * scale + bb;
                store_out(&Cw[(size_t)(crow + r) * N + ccol], val);
            }
        }
    }
}

// --- row softmax in place over bf16 S[4096][4096] -------------------------
__global__ __launch_bounds__(256) void softmax_bf16(short* __restrict__ S)
{
    const int row = blockIdx.x;
    short8* r8 = (short8*)(S + (size_t)row * 4096);
    const int t = threadIdx.x;

    float x[16];
    #pragma unroll
    for (int i = 0; i < 2; ++i) {
        short8 raw = r8[t + 256 * i];
        #pragma unroll
        for (int j = 0; j < 8; ++j) x[8 * i + j] = bf2f(raw[j]);
    }
    float m = -1e30f;
    #pragma unroll
    for (int i = 0; i < 16; ++i) m = fmaxf(m, x[i]);
    #pragma unroll
    for (int off = 32; off > 0; off >>= 1) m = fmaxf(m, __shfl_xor(m, off));

    __shared__ float redm[4], reds[4];
    const int wv = t >> 6;
    if ((t & 63) == 0) redm[wv] = m;
    __syncthreads();
    m = fmaxf(fmaxf(redm[0], redm[1]), fmaxf(redm[2], redm[3]));

    float s = 0.f;
    #pragma unroll
    for (int i = 0; i < 16; ++i) { x[i] = __expf(x[i] - m); s += x[i]; }
    #pragma unroll
    for (int off = 32; off > 0; off >>= 1) s += __shfl_xor(s, off);
    if ((t & 63) == 0) reds[wv] = s;
    __syncthreads();
    s = reds[0] + reds[1] + reds[2] + reds[3];
    const float inv = 1.f / s;

    #pragma unroll
    for (int i = 0; i < 2; ++i) {
        short8 o;
        #pragma unroll
        for (int j = 0; j < 8; ++j) o[j] = f2bf(x[8 * i + j] * inv);
        r8[t + 256 * i] = o;
    }
}

// --- out += p1 + p2 (+ p3) (split-K combine, in place) --------------------
__global__ __launch_bounds__(256) void combine(
    float* __restrict__ out, const float* __restrict__ a,
    const float* __restrict__ b, const float* __restrict__ c, int np)
{
    for (int i = blockIdx.x * 256 + threadIdx.x; i < 1048576; i += 256 * 1024) {
        float4 o = ((const float4*)out)[i];
        float4 x = ((const float4*)a)[i];
        float4 y = ((const float4*)b)[i];
        o.x += x.x + y.x; o.y += x.y + y.y;
        o.z += x.z + y.z; o.w += x.w + y.w;
        if (np == 3) {
            float4 w = ((const float4*)c)[i];
            o.x += w.x; o.y += w.y; o.z += w.z; o.w += w.w;
        }
        ((float4*)out)[i] = o;
    }
}

extern "C" void kernel_launch(void* const* d_in, const int* in_sizes, int n_in,
                              void* d_out, int out_size, void* d_ws, size_t ws_size,
                              hipStream_t stream)
{
    const float* q  = (const float*)d_in[0];
    const float* k  = (const float*)d_in[1];
    const float* v  = (const float*)d_in[2];
    const float* Wq = (const float*)d_in[3];
    const float* bq = (const float*)d_in[4];
    const float* Wk = (const float*)d_in[5];
    const float* bk = (const float*)d_in[6];
    const float* Wv = (const float*)d_in[7];
    const float* bv = (const float*)d_in[8];
    float* out = (float*)d_out;

    char* ws = (char*)d_ws;
    const size_t MB = 1ull << 20;
    short* Wt = (short*)(ws + 0);           // 3 x 1M shorts
    short* xb = (short*)(ws + 6 * MB);      // 3 x 4M shorts
    short* pr = (short*)(ws + 30 * MB);     // 3 x 4M shorts: Q, K, Vn
    short* S  = (short*)(ws + 46 * MB);     // 16M shorts (overwrites dead Vn)
    short* Vt = (short*)(ws + 78 * MB);     // 4M shorts
    float* p1 = (float*)(ws + 0);           // dead Wt/xb region by PV time
    float* p2 = (float*)(ws + 16 * MB);
    float* p3 = (float*)(ws + 86 * MB);     // extra space, if available
    const int SK = (ws_size >= 102 * MB) ? 4 : 3;

    // 1) W^T + cast, q/k/v cast
    prep_w<<<dim3(16, 16, 3), 256, 0, stream>>>(Wq, Wk, Wv, Wt);
    cast_qkv<<<dim3(1024, 1, 3), 256, 0, stream>>>(q, k, v, xb);
    // 2) projections: Q,K,Vn -> pr (z-batched)
    gemm256<short, 1><<<dim3(4, 16, 3), 512, 0, stream>>>(
        xb, Wt, bq, bk, bv, pr, nullptr, nullptr, nullptr,
        4096, 1024, 1024, 1024, 1.f, 32, 32, 0);
    // 3) Vn -> Vt (then Vn region is dead; S may overwrite it)
    transpose_v<<<dim3(16, 64), 256, 0, stream>>>(pr + 8 * 1024 * 1024, Vt);
    // 4) S = Q K^T / 32
    gemm256<short, 0><<<dim3(16, 16), 512, 0, stream>>>(
        pr, pr + 4 * 1024 * 1024, nullptr, nullptr, nullptr, S,
        nullptr, nullptr, nullptr,
        4096, 4096, 1024, 1024, 0.03125f, 32, 32, 0);
    // 5) softmax rows in place (bf16)
    softmax_bf16<<<4096, 256, 0, stream>>>(S);
    // 6) partials = P @ V  (split-K; z=0 writes straight to out)
    if (SK == 4) {
        gemm256<float, 2><<<dim3(4, 16, 4), 512, 0, stream>>>(
            S, Vt, nullptr, nullptr, nullptr, out, p1, p2, p3,
            4096, 1024, 4096, 4096, 1.f, 32, 32, 1024);
        combine<<<1024, 256, 0, stream>>>(out, p1, p2, p3, 3);
    } else {
        gemm256<float, 2><<<dim3(4, 16, 3), 512, 0, stream>>>(
            S, Vt, nullptr, nullptr, nullptr, out, p1, p2, nullptr,
            4096, 1024, 4096, 4096, 1.f, 42, 44, 1344);
        combine<<<1024, 256, 0, stream>>>(out, p1, p2, nullptr, 2);
    }
}

// Round 2
// 253.301 us; speedup vs baseline: 1.0636x; 1.0247x over previous
//
#include <hip/hip_runtime.h>

// ---------------------------------------------------------------------------
// context = softmax((q@Wq+bq)(k@Wk+bk)^T / 32) @ (v@Wv+bv)
// S=4096, H=D=1024. fp32 in/out, bf16 MFMA internally.
//
// GEMM core (gemm256): 256x256 tile, 512 threads (8 waves, 2x4), K processed
// in 32-wide chunks through a 4-unit LDS ring (4 x 32KB = 128KB).
// Each chunk = TWO 16-MFMA sub-phases (m201 granularity):
//   sub0: {ds_read af[0..3]+bfr[0..3] | stage A-half c+3 | barrier |
//          setprio(1) 16 MFMA setprio(0) | barrier}
//   sub1: {ds_read af[4..7] (B reused in regs) | stage B-half c+3 | barrier |
//          setprio(1) 16 MFMA setprio(0) | vmcnt(8) | barrier}
// vmcnt never drains to 0 in the main loop (T4).
//
// LDS bank swizzle (T2, both-sides-or-neither): logical 16B col k8 of row r
// lives at physical col k8 ^ ((r>>1)&3). Reads use lq ^ ((lr>>1)&3) (lane-
// constant); staging keeps the linear global_load_lds dest and pre-swizzles
// the per-lane GLOBAL k-offset: (l&3) ^ ((l>>3)&3). 8 consecutive lanes then
// hit all 8 bank-slots (bijective) -> conflict-free ds_read_b128.
//
// ws layout (MB):
//   [ 0, 6)  Wt  bf16 [3][1024][1024]      (W^T, per projection)
//   [ 6,30)  xb  bf16 [3][4096][1024]      (q,k,v cast)
//   [30,54)  pr  bf16 [3][4096][1024]      (Q,K,Vn projections; z-contiguous)
//   [46,78)  S   bf16 [4096][4096]         (overwrites dead Vn after transpose)
//   [78,86)  Vt  bf16 [1024][4096]
//   [ 0,16)  p1, [16,32) p2  fp32 partials (dead Wt/xb region at PV time)
//   [86,102) p3 fp32 partial               (only if ws_size >= 102MB -> SK=4)
// ---------------------------------------------------------------------------

typedef short short4v __attribute__((ext_vector_type(4)));
typedef short short8  __attribute__((ext_vector_type(8)));
typedef float f32x4   __attribute__((ext_vector_type(4)));

#define MFMA16 __builtin_amdgcn_mfma_f32_16x16x32_bf16

__device__ __forceinline__ short f2bf(float f) {
    union { float f; unsigned u; } x; x.f = f;
    unsigned r = (x.u + 0x7FFFu + ((x.u >> 16) & 1u)) >> 16;  // RNE
    return (short)r;
}
__device__ __forceinline__ float bf2f(short s) {
    union { unsigned u; float f; } x;
    x.u = ((unsigned)(unsigned short)s) << 16; return x.f;
}
__device__ __forceinline__ void store_out(short* p, float v) { *p = f2bf(v); }
__device__ __forceinline__ void store_out(float* p, float v) { *p = v; }

// async global->LDS, 16B/lane. LDS dest = wave-uniform base + lane*16.
__device__ __forceinline__ void gl2lds(const short* g, short* l) {
    __builtin_amdgcn_global_load_lds(
        (const __attribute__((address_space(1))) void*)g,
        (__attribute__((address_space(3))) void*)l, 16, 0, 0);
}

// --- W[k][n] fp32 -> Wt[z][n][k] bf16 ------------------------------------
__global__ __launch_bounds__(256) void prep_w(
    const float* __restrict__ W0, const float* __restrict__ W1,
    const float* __restrict__ W2, short* __restrict__ Wt)
{
    __shared__ float tile[64][65];
    const float* W = blockIdx.z == 0 ? W0 : (blockIdx.z == 1 ? W1 : W2);
    short* T = Wt + (size_t)blockIdx.z * 1048576;
    const int c0 = blockIdx.x * 64;
    const int r0 = blockIdx.y * 64;
    const int tx = threadIdx.x & 63;
    const int ty = threadIdx.x >> 6;
    #pragma unroll
    for (int p = 0; p < 16; ++p) {
        int r = ty + p * 4;
        tile[r][tx] = W[(size_t)(r0 + r) * 1024 + c0 + tx];
    }
    __syncthreads();
    #pragma unroll
    for (int p = 0; p < 16; ++p) {
        int r = ty + p * 4;
        T[(size_t)(c0 + r) * 1024 + r0 + tx] = f2bf(tile[tx][r]);
    }
}

// --- q,k,v fp32 -> xb bf16 -----------------------------------------------
__global__ __launch_bounds__(256) void cast_qkv(
    const float* __restrict__ q, const float* __restrict__ k,
    const float* __restrict__ v, short* __restrict__ xb)
{
    const float* src = blockIdx.z == 0 ? q : (blockIdx.z == 1 ? k : v);
    short* dst = xb + (size_t)blockIdx.z * 4194304;
    for (int i = blockIdx.x * 256 + threadIdx.x; i < 1048576; i += 256 * 1024) {
        float4 f = ((const float4*)src)[i];
        short4v o;
        o[0] = f2bf(f.x); o[1] = f2bf(f.y); o[2] = f2bf(f.z); o[3] = f2bf(f.w);
        ((short4v*)dst)[i] = o;
    }
}

// --- Vn bf16 [4096][1024] -> Vt bf16 [1024][4096] -------------------------
__global__ __launch_bounds__(256) void transpose_v(
    const short* __restrict__ src, short* __restrict__ dst)
{
    __shared__ short t[64][65];
    const int c0 = blockIdx.x * 64;   // src col block (dst row block)
    const int r0 = blockIdx.y * 64;   // src row block
    const int tx = threadIdx.x & 63;
    const int ty = threadIdx.x >> 6;
    #pragma unroll
    for (int p = 0; p < 16; ++p) {
        const int r = p * 4 + ty;
        t[r][tx] = src[(size_t)(r0 + r) * 1024 + c0 + tx];
    }
    __syncthreads();
    #pragma unroll
    for (int p = 0; p < 16; ++p) {
        const int r = p * 4 + ty;
        dst[(size_t)(c0 + r) * 4096 + r0 + tx] = t[tx][r];
    }
}

// --- bf16 GEMM core: C = scale*(A @ Bt^T) [+ bias] ------------------------
// 256x256 tile, 8 waves (2Mx4N), 4-unit LDS ring of K=32 chunks.
// MODE 0: plain. MODE 1: z selects {A,Bt,C,bias} (batched projections).
// MODE 2: z is split-K index; C-dst = {C, P1, P2, P3}[z].
template <typename TOut, int MODE>
__global__ __launch_bounds__(512, 2) void gemm256(
    const short* __restrict__ A, const short* __restrict__ Bt,
    const float* __restrict__ b0, const float* __restrict__ b1,
    const float* __restrict__ b2,
    TOut* __restrict__ C, float* __restrict__ P1, float* __restrict__ P2,
    float* __restrict__ P3,
    int M, int N, int lda, int ldb, float scale,
    int nc, int nc_last, int kstep)
{
    // 4 units x { A [256 rows][64B] , B [256 rows][64B] } = 4 x 32KB = 128KB
    __shared__ short Lds[65536];

    const int t    = threadIdx.x;
    const int lane = t & 63;
    const int wv   = t >> 6;

    // ---- grid swizzle (XCD L2 locality). HW round-robins bid%8 -> XCD. ---
    int m0, n0;
    {
        const int nb  = gridDim.x;                    // n-tiles
        const int bid = blockIdx.y * nb + blockIdx.x;
        if (nb == 16 && gridDim.y == 16) {
            // 2x4 XCD rectangles: XCD x gets an 8m x 4n block of tiles.
            const int x = bid & 7, i = bid >> 3;
            m0 = ((x & 1) * 8 + (i & 7)) * 256;
            n0 = ((x >> 1) * 4 + (i >> 3)) * 256;
        } else {
            // band swizzle: 8 m-tiles per band, XCD x keeps m == x (mod 8).
            const int band   = bid / (8 * nb);
            const int within = bid - band * 8 * nb;
            m0 = (band * 8 + (within & 7)) * 256;
            n0 = (within >> 3) * 256;
        }
    }

    const float* bias = nullptr;
    int kbeg = 0;
    TOut* Cw = C;
    if constexpr (MODE == 1) {
        const int z = blockIdx.z;
        A  += (size_t)z * M * lda;
        Bt += (size_t)z * N * ldb;
        Cw  = C + (size_t)z * M * N;
        bias = z == 0 ? b0 : (z == 1 ? b1 : b2);
    }
    if constexpr (MODE == 2) {
        const int z = blockIdx.z;
        kbeg = z * kstep;
        if (z == (int)gridDim.z - 1) nc = nc_last;
        Cw = (TOut*)(z == 0 ? (float*)C : (z == 1 ? P1 : (z == 2 ? P2 : P3)));
    }
    (void)b0; (void)b1; (void)b2; (void)P1; (void)P2; (void)P3;
    (void)nc_last; (void)kstep;

    // ---- staging map: per chunk, each wave issues 4 gl2lds (1KB each). ---
    // lane l -> row = wv*16 + (l>>2); global 16B-col pre-swizzled with the
    // same involution the reads use: (l&3) ^ ((l>>3)&3)  [key=(row>>1)&3].
    const int srow = lane >> 2;
    const int skof = ((lane & 3) ^ ((lane >> 3) & 3)) * 8;
    const short* pA0 = A  + (size_t)(m0 + wv * 16 + srow) * lda + kbeg + skof;
    const short* pA1 = pA0 + (size_t)128 * lda;
    const short* pB0 = Bt + (size_t)(n0 + wv * 16 + srow) * ldb + kbeg + skof;
    const short* pB1 = pB0 + (size_t)128 * ldb;
    short* sA0 = Lds + wv * 512;            // wave-uniform LDS bases (shorts)
    short* sA1 = Lds + 4096  + wv * 512;
    short* sB0 = Lds + 8192  + wv * 512;
    short* sB1 = Lds + 12288 + wv * 512;

    // ---- fragment read map (16x16x32: lane = lr + 16*lq) -----------------
    // physical 16B col = lq ^ ((row>>1)&3); row base is a multiple of 16 so
    // the key reduces to (lr>>1)&3 -> lane-constant pointer.
    const int wm = wv >> 2, wn = wv & 3;
    const int lr = lane & 15, lq = lane >> 4;
    const int pcol = lq ^ ((lr >> 1) & 3);
    const short* rdA = Lds + (wm * 128 + lr) * 32 + pcol * 8;
    const short* rdB = Lds + 8192 + (wn * 64 + lr) * 32 + pcol * 8;

    f32x4 acc[8][4];
    #pragma unroll
    for (int i = 0; i < 8; ++i)
        #pragma unroll
        for (int j = 0; j < 4; ++j) { f32x4 z4 = {0.f,0.f,0.f,0.f}; acc[i][j] = z4; }

#define STAGE_A(c) {                                                      \
    const int su_ = (c) & 3;                                              \
    const size_t ko_ = (size_t)(c) * 32;                                  \
    gl2lds(pA0 + ko_, sA0 + su_ * 16384);                                 \
    gl2lds(pA1 + ko_, sA1 + su_ * 16384); }
#define STAGE_B(c) {                                                      \
    const int su_ = (c) & 3;                                              \
    const size_t ko_ = (size_t)(c) * 32;                                  \
    gl2lds(pB0 + ko_, sB0 + su_ * 16384);                                 \
    gl2lds(pB1 + ko_, sB1 + su_ * 16384); }

    // prologue: chunks 0,1,2 in flight; wait chunk 0 (8 = 2 chunks x 4).
    STAGE_A(0); STAGE_B(0);
    STAGE_A(1); STAGE_B(1);
    STAGE_A(2); STAGE_B(2);
    asm volatile("s_waitcnt vmcnt(8)" ::: "memory");
    __builtin_amdgcn_s_barrier();

    // Chunk c: two 16-MFMA sub-phases. Reads chunk c (ready: prev chunk
    // ended vmcnt(8)+barrier). Stages chunk c+3 into the slot chunk c-1
    // vacated (its reads completed before chunk c-1's final barrier).
#define PHASE(c, DOSTAGE, VMN) {                                          \
    const int u_ = (c) & 3;                                               \
    const short* rA_ = rdA + u_ * 16384;                                  \
    const short* rB_ = rdB + u_ * 16384;                                  \
    short8 af[4], bfr[4];                                                 \
    _Pragma("unroll") for (int i = 0; i < 4; ++i)                         \
        af[i] = *(const short8*)(rA_ + i * 512);                          \
    _Pragma("unroll") for (int j = 0; j < 4; ++j)                         \
        bfr[j] = *(const short8*)(rB_ + j * 512);                         \
    if (DOSTAGE) STAGE_A((c) + 3);                                        \
    __builtin_amdgcn_s_barrier();                                         \
    __builtin_amdgcn_s_setprio(1);                                        \
    _Pragma("unroll") for (int i = 0; i < 4; ++i)                         \
        _Pragma("unroll") for (int j = 0; j < 4; ++j)                     \
            acc[i][j] = MFMA16(af[i], bfr[j], acc[i][j], 0, 0, 0);        \
    __builtin_amdgcn_s_setprio(0);                                        \
    __builtin_amdgcn_s_barrier();                                         \
    _Pragma("unroll") for (int i = 0; i < 4; ++i)                         \
        af[i] = *(const short8*)(rA_ + (4 + i) * 512);                    \
    if (DOSTAGE) STAGE_B((c) + 3);                                        \
    __builtin_amdgcn_s_barrier();                                         \
    __builtin_amdgcn_s_setprio(1);                                        \
    _Pragma("unroll") for (int i = 0; i < 4; ++i)                         \
        _Pragma("unroll") for (int j = 0; j < 4; ++j)                     \
            acc[4 + i][j] = MFMA16(af[i], bfr[j], acc[4 + i][j], 0, 0, 0);\
    __builtin_amdgcn_s_setprio(0);                                        \
    if ((VMN) == 8)      asm volatile("s_waitcnt vmcnt(8)" ::: "memory"); \
    else if ((VMN) == 4) asm volatile("s_waitcnt vmcnt(4)" ::: "memory"); \
    else if ((VMN) == 0) asm volatile("s_waitcnt vmcnt(0)" ::: "memory"); \
    if ((VMN) >= 0) __builtin_amdgcn_s_barrier(); }

    #pragma unroll 4
    for (int c = 0; c < nc - 3; ++c) PHASE(c, 1, 8);
    PHASE(nc - 3, 0, 4);
    PHASE(nc - 2, 0, 0);
    PHASE(nc - 1, 0, -1);
#undef PHASE
#undef STAGE_A
#undef STAGE_B

    // ---- epilogue: C/D layout col=lane&15, row=(lane>>4)*4+reg -----------
    #pragma unroll
    for (int i = 0; i < 8; ++i) {
        const int crow = m0 + wm * 128 + i * 16 + lq * 4;
        #pragma unroll
        for (int j = 0; j < 4; ++j) {
            const int ccol = n0 + wn * 64 + j * 16 + lr;
            float bb = 0.f;
            if constexpr (MODE == 1) bb = bias[ccol];
            #pragma unroll
            for (int r = 0; r < 4; ++r) {
                float val = acc[i][j][r] * scale + bb;
                store_out(&Cw[(size_t)(crow + r) * N + ccol], val);
            }
        }
    }
}

// --- row softmax in place over bf16 S[4096][4096] -------------------------
__global__ __launch_bounds__(256) void softmax_bf16(short* __restrict__ S)
{
    const int row = blockIdx.x;
    short8* r8 = (short8*)(S + (size_t)row * 4096);
    const int t = threadIdx.x;

    float x[16];
    #pragma unroll
    for (int i = 0; i < 2; ++i) {
        short8 raw = r8[t + 256 * i];
        #pragma unroll
        for (int j = 0; j < 8; ++j) x[8 * i + j] = bf2f(raw[j]);
    }
    float m = -1e30f;
    #pragma unroll
    for (int i = 0; i < 16; ++i) m = fmaxf(m, x[i]);
    #pragma unroll
    for (int off = 32; off > 0; off >>= 1) m = fmaxf(m, __shfl_xor(m, off));

    __shared__ float redm[4], reds[4];
    const int wv = t >> 6;
    if ((t & 63) == 0) redm[wv] = m;
    __syncthreads();
    m = fmaxf(fmaxf(redm[0], redm[1]), fmaxf(redm[2], redm[3]));

    float s = 0.f;
    #pragma unroll
    for (int i = 0; i < 16; ++i) { x[i] = __expf(x[i] - m); s += x[i]; }
    #pragma unroll
    for (int off = 32; off > 0; off >>= 1) s += __shfl_xor(s, off);
    if ((t & 63) == 0) reds[wv] = s;
    __syncthreads();
    s = reds[0] + reds[1] + reds[2] + reds[3];
    const float inv = 1.f / s;

    #pragma unroll
    for (int i = 0; i < 2; ++i) {
        short8 o;
        #pragma unroll
        for (int j = 0; j < 8; ++j) o[j] = f2bf(x[8 * i + j] * inv);
        r8[t + 256 * i] = o;
    }
}

// --- out += p1 + p2 (+ p3) (split-K combine, in place) --------------------
__global__ __launch_bounds__(256) void combine(
    float* __restrict__ out, const float* __restrict__ a,
    const float* __restrict__ b, const float* __restrict__ c, int np)
{
    for (int i = blockIdx.x * 256 + threadIdx.x; i < 1048576; i += 256 * 1024) {
        float4 o = ((const float4*)out)[i];
        float4 x = ((const float4*)a)[i];
        float4 y = ((const float4*)b)[i];
        o.x += x.x + y.x; o.y += x.y + y.y;
        o.z += x.z + y.z; o.w += x.w + y.w;
        if (np == 3) {
            float4 w = ((const float4*)c)[i];
            o.x += w.x; o.y += w.y; o.z += w.z; o.w += w.w;
        }
        ((float4*)out)[i] = o;
    }
}

extern "C" void kernel_launch(void* const* d_in, const int* in_sizes, int n_in,
                              void* d_out, int out_size, void* d_ws, size_t ws_size,
                              hipStream_t stream)
{
    const float* q  = (const float*)d_in[0];
    const float* k  = (const float*)d_in[1];
    const float* v  = (const float*)d_in[2];
    const float* Wq = (const float*)d_in[3];
    const float* bq = (const float*)d_in[4];
    const float* Wk = (const float*)d_in[5];
    const float* bk = (const float*)d_in[6];
    const float* Wv = (const float*)d_in[7];
    const float* bv = (const float*)d_in[8];
    float* out = (float*)d_out;

    char* ws = (char*)d_ws;
    const size_t MB = 1ull << 20;
    short* Wt = (short*)(ws + 0);           // 3 x 1M shorts
    short* xb = (short*)(ws + 6 * MB);      // 3 x 4M shorts
    short* pr = (short*)(ws + 30 * MB);     // 3 x 4M shorts: Q, K, Vn
    short* S  = (short*)(ws + 46 * MB);     // 16M shorts (overwrites dead Vn)
    short* Vt = (short*)(ws + 78 * MB);     // 4M shorts
    float* p1 = (float*)(ws + 0);           // dead Wt/xb region by PV time
    float* p2 = (float*)(ws + 16 * MB);
    float* p3 = (float*)(ws + 86 * MB);     // extra space, if available
    const int SK = (ws_size >= 102 * MB) ? 4 : 3;

    // 1) W^T + cast, q/k/v cast
    prep_w<<<dim3(16, 16, 3), 256, 0, stream>>>(Wq, Wk, Wv, Wt);
    cast_qkv<<<dim3(1024, 1, 3), 256, 0, stream>>>(q, k, v, xb);
    // 2) projections: Q,K,Vn -> pr (z-batched)
    gemm256<short, 1><<<dim3(4, 16, 3), 512, 0, stream>>>(
        xb, Wt, bq, bk, bv, pr, nullptr, nullptr, nullptr,
        4096, 1024, 1024, 1024, 1.f, 32, 32, 0);
    // 3) Vn -> Vt (then Vn region is dead; S may overwrite it)
    transpose_v<<<dim3(16, 64), 256, 0, stream>>>(pr + 8 * 1024 * 1024, Vt);
    // 4) S = Q K^T / 32
    gemm256<short, 0><<<dim3(16, 16), 512, 0, stream>>>(
        pr, pr + 4 * 1024 * 1024, nullptr, nullptr, nullptr, S,
        nullptr, nullptr, nullptr,
        4096, 4096, 1024, 1024, 0.03125f, 32, 32, 0);
    // 5) softmax rows in place (bf16)
    softmax_bf16<<<4096, 256, 0, stream>>>(S);
    // 6) partials = P @ V  (split-K; z=0 writes straight to out)
    if (SK == 4) {
        gemm256<float, 2><<<dim3(4, 16, 4), 512, 0, stream>>>(
            S, Vt, nullptr, nullptr, nullptr, out, p1, p2, p3,
            4096, 1024, 4096, 4096, 1.f, 32, 32, 1024);
        combine<<<1024, 256, 0, stream>>>(out, p1, p2, p3, 3);
    } else {
        gemm256<float, 2><<<dim3(4, 16, 3), 512, 0, stream>>>(
            S, Vt, nullptr, nullptr, nullptr, out, p1, p2, nullptr,
            4096, 1024, 4096, 4096, 1.f, 42, 44, 1344);
        combine<<<1024, 256, 0, stream>>>(out, p1, p2, nullptr, 2);
    }
}